// Round 11
// baseline (97.895 us; speedup 1.0000x reference)
//
#include <hip/hip_runtime.h>

// Fused LSTM B=16384, T=60, IN=1, H=50, OUT=1 — balanced 4-wave, 4 blk/CU.
// 1024 blocks x 256 thr (4 waves), 16 batches/block -> 4 blocks/CU =
// 16 waves/CU = 4 waves/SIMD (R5's occupancy) with R10's de-fatted math
// (13 M-tiles, batched 4-term-reciprocal nonlinearity) and BALANCED tile
// distribution {4,3,3,3}: heavy wave hv rotated per block so each SIMD's
// resident waves carry ~13 slots/step (R10's {4,4,4,1} made wave-0..2
// SIMDs carry 16 while wave-3 SIMDs carried 4 -> ~23% idle by convoy).
// unit u = 4T+du, D-row = 4du+gate; identity k-map (k=unit), bias k=62,
// x_t k=63. H fp16 [row=cl][64] chunk(16B)-XOR-swizzled double buffer,
// one barrier/step. Weights fp16(hi) A-frags in VGPRs; c fp32 in regs.

namespace {
constexpr int TS = 60;

typedef _Float16 half8 __attribute__((ext_vector_type(8)));
typedef _Float16 half2v __attribute__((ext_vector_type(2)));
typedef float f32x4 __attribute__((ext_vector_type(4)));

__device__ __forceinline__ float fexp2(float x) { return __builtin_amdgcn_exp2f(x); }
__device__ __forceinline__ float frcp(float x) { return __builtin_amdgcn_rcpf(x); }
__device__ __forceinline__ f32x4 mfma16(half8 a, half8 b, f32x4 c) {
  return __builtin_amdgcn_mfma_f32_16x16x32_f16(a, b, c, 0, 0, 0);
}
}  // namespace

__global__ __launch_bounds__(256, 4) void lstm_bal(
    const float* __restrict__ x,      // [B][60]
    const float* __restrict__ w_ih,   // [200]
    const float* __restrict__ w_hh,   // [200][50]
    const float* __restrict__ b_ih,   // [200]
    const float* __restrict__ b_hh,   // [200]
    const float* __restrict__ w_lin,  // [3000]
    const float* __restrict__ b_lin,  // [1]
    float* __restrict__ out)          // [B]
{
  __shared__ __align__(16) _Float16 Hs[2][16 * 64];  // dbuf, 4 KB total
  __shared__ float WL[TS * 64];  // 15.36 KB [t][u], 0-padded
  __shared__ float XL[TS * 16];  // 3.84 KB [t][b]
  __shared__ float OB[4][16];    // 256 B

  const int tid = threadIdx.x;
  const int lane = tid & 63;
  const int wv = tid >> 6;   // 0..3
  const int g = lane >> 4;   // B k-owner / D row-block (du)
  const int cl = lane & 15;  // batch; A/B/D column
  const int s8 = cl & 7;
  const int bid = blockIdx.x;
  const long bbase = (long)bid * 16;

  // heavy-wave rotation: distinct within a CU cohort whether the cohort is
  // {b, b+256, b+512, b+768} (XCD-strided) or {4c..4c+3} (sequential).
  const int hv = (bid + (bid >> 8)) & 3;
  const int ntile = 3 + (wv == hv);
  const int tbase = 3 * wv + (wv > hv ? 1 : 0);

  // ---- stage XL[t][b] ----
  for (int i = tid; i < TS * 16; i += 256) {
    const int b = i / TS, t = i - b * TS;
    XL[t * 16 + b] = x[bbase * TS + i];
  }
  // ---- stage WL[t][u] ----
  for (int i = tid; i < TS * 64; i += 256) {
    const int t = i >> 6, u = i & 63;
    WL[i] = (u < 50) ? w_lin[t * 50 + u] : 0.0f;
  }
  // ---- zero both H buffers (h0=0; pad k-slots stay 0) ----
  for (int i = tid; i < 1024; i += 256) ((unsigned*)Hs)[i] = 0u;

  // ---- gather this wave's A-fragments (fp32 -> fp16), once ----
  // tile T: A-row m=cl -> (du=cl>>2, gate=cl&3), unit uA = 4T+du,
  // orig gate-row = gate*50+uA. k-slot 32kc+8g+e: k<50 -> w_hh col k,
  // 62 -> bias, 63 -> w_ih.
  half8 A[4][2];
  {
    const int gate = cl & 3, du = cl >> 2;
#pragma unroll
    for (int tau = 0; tau < 4; ++tau) {
      const int T = tbase + tau;
      const int uA = 4 * T + du;
      const int orig = gate * 50 + uA;
      const bool valid = (tau < ntile) && (uA < 50);
#pragma unroll
      for (int kc = 0; kc < 2; ++kc) {
        half8 fr;
#pragma unroll
        for (int e = 0; e < 8; ++e) {
          const int k = kc * 32 + 8 * g + e;
          float v = 0.0f;
          if (valid) {
            if (k < 50) v = w_hh[orig * 50 + k];
            else if (k == 62) v = b_ih[orig] + b_hh[orig];
            else if (k == 63) v = w_ih[orig];
          }
          fr[e] = (_Float16)v;
        }
        A[tau][kc] = fr;
      }
    }
  }
  __syncthreads();

  // ---- specials in buf0: k=62 -> 1.0, k=63 -> x_0 (chunk 7, ofs 6,7) ----
  if (wv == 3 && g == 3) {
    const half2v sp = {(_Float16)1.0f, (_Float16)XL[cl]};
    *(half2v*)&Hs[0][cl * 64 + ((7 ^ s8) << 3) + 6] = sp;
  }
  __syncthreads();

  // B-frag read offsets (halves): kc0 -> chunk g, kc1 -> chunk 4+g
  const int rh0 = cl * 64 + ((g ^ s8) << 3);
  const int rh1 = cl * 64 + (((4 | g) ^ s8) << 3);

  float c[4] = {0.f, 0.f, 0.f, 0.f};
  float oacc = 0.0f;

  constexpr float L1 = 1.4426950408889634f;  // log2(e)
  constexpr float L2 = 2.8853900817779268f;  // 2*log2(e)

#define DO_TILES(NT)                                                          \
  {                                                                           \
    f32x4 acc[NT];                                                            \
    _Pragma("unroll") for (int tau = 0; tau < NT; ++tau) {                    \
      f32x4 a = {0.f, 0.f, 0.f, 0.f};                                         \
      a = mfma16(A[tau][0], B0, a);                                           \
      a = mfma16(A[tau][1], B1, a);                                           \
      acc[tau] = a;                                                           \
    }                                                                         \
    _Pragma("unroll") for (int tau = 0; tau < NT; ++tau) {                    \
      const int u = 4 * (tbase + tau) + g;                                    \
      const float wlv = WL[t * 64 + u];                                       \
      const int widx = cl * 64 + (((u >> 3) ^ s8) << 3) + (u & 7);            \
      const float E1 = fexp2(-L1 * acc[tau][0]);                              \
      const float E2 = fexp2(-L1 * acc[tau][1]);                              \
      const float E3 = fexp2(-L1 * acc[tau][3]);                              \
      const float E4 = fexp2(L2 * acc[tau][2]);                               \
      const float P1 = 1.0f + E1, P2 = 1.0f + E2;                             \
      const float P3 = 1.0f + E3, P4 = 1.0f + E4;                             \
      const float p12 = P1 * P2, p34 = P3 * P4;                               \
      const float r = frcp(p12 * p34);                                        \
      const float r12 = r * p34, r34 = r * p12;                               \
      const float si = r12 * P2, sf = r12 * P1, so = r34 * P4;                \
      const float tg = fmaf(-2.0f, r34 * P3, 1.0f);                           \
      const float cn = fmaf(sf, c[tau], si * tg);                             \
      c[tau] = cn;                                                            \
      const float Ec = fexp2(L2 * cn);                                        \
      const float tc = fmaf(-2.0f, frcp(1.0f + Ec), 1.0f);                    \
      const float hn = so * tc;                                               \
      oacc = fmaf(hn, wlv, oacc);                                             \
      HW[widx] = (_Float16)hn;                                                \
    }                                                                         \
  }

#pragma unroll 1
  for (int t = 0; t < TS; ++t) {
    const int p = t & 1;
    const _Float16* HR = &Hs[p][0];
    _Float16* HW = &Hs[p ^ 1][0];
    const half8 B0 = *(const half8*)&HR[rh0];
    const half8 B1 = *(const half8*)&HR[rh1];

    if (wv == hv) {
      DO_TILES(4);
    } else {
      DO_TILES(3);
    }
    if (wv == 3 && g == 3) {  // specials for next step
      const int tn = (t + 1 < TS) ? (t + 1) : (TS - 1);
      const half2v sp = {(_Float16)1.0f, (_Float16)XL[tn * 16 + cl]};
      *(half2v*)&HW[cl * 64 + ((7 ^ s8) << 3) + 6] = sp;
    }
    __syncthreads();
  }
#undef DO_TILES

  // ---- reduce over g (shfl), then over waves (LDS) ----
  oacc += __shfl_xor(oacc, 32);
  oacc += __shfl_xor(oacc, 16);
  if (lane < 16) OB[wv][cl] = oacc;
  __syncthreads();
  if (tid < 16) {
    float s = b_lin[0];
#pragma unroll
    for (int q = 0; q < 4; ++q) s += OB[q][tid];
    out[bbase + tid] = s;
  }
}

extern "C" void kernel_launch(void* const* d_in, const int* in_sizes, int n_in,
                              void* d_out, int out_size, void* d_ws, size_t ws_size,
                              hipStream_t stream) {
  const float* x     = (const float*)d_in[0];
  const float* w_ih  = (const float*)d_in[1];
  const float* w_hh  = (const float*)d_in[2];
  const float* b_ih  = (const float*)d_in[3];
  const float* b_hh  = (const float*)d_in[4];
  const float* w_lin = (const float*)d_in[5];
  const float* b_lin = (const float*)d_in[6];
  float* out = (float*)d_out;

  dim3 grid(16384 / 16);  // 1024 blocks -> 4 per CU, 4 waves/SIMD
  dim3 block(256);
  lstm_bal<<<grid, block, 0, stream>>>(x, w_ih, w_hh, b_ih, b_hh, w_lin,
                                       b_lin, out);
}

// Round 12
// 93.090 us; speedup vs baseline: 1.0516x; 1.0516x over previous
//
#include <hip/hip_runtime.h>

// Fused LSTM B=16384, T=60, IN=1, H=50, OUT=1 — 8-wave, 4-group, 1 grp/wave.
// 256 blocks x 512 thr (1 block/CU). Block owns 64 batches = 4 independent
// 16-batch groups. Waves 2g,2g+1 M-split group g's 13 tiles {7,6}. Each wave
// touches ONE group: per step only 2 ds_read_b128 + <=7 slots (2 MFMA each)
// + <=7 ds_write_b16 + 1 barrier. Per SIMD: 2 waves x ~6.5 slots over 2
// DIFFERENT groups -> 13 independent nonlin chains to interleave.
// unit u = 4T+du (du = lane>>4 at D, =cl>>2 at A-row); identity k-map,
// bias k=62, x_t k=63. H fp16 [row=cl][64] chunk-XOR swizzled, dbuf/group.
// Math: fp16(hi) weights, batched 4-term-reciprocal nonlin (R8-verified).
// Evidence R4-R11: wall ~4000 cyc/step invariant to issue/occupancy/balance;
// only in-wave chain count helped. This maximizes chains/SIMD at min DS.

namespace {
constexpr int TS = 60;

typedef _Float16 half8 __attribute__((ext_vector_type(8)));
typedef _Float16 half2v __attribute__((ext_vector_type(2)));
typedef float f32x4 __attribute__((ext_vector_type(4)));

__device__ __forceinline__ float fexp2(float x) { return __builtin_amdgcn_exp2f(x); }
__device__ __forceinline__ float frcp(float x) { return __builtin_amdgcn_rcpf(x); }
__device__ __forceinline__ f32x4 mfma16(half8 a, half8 b, f32x4 c) {
  return __builtin_amdgcn_mfma_f32_16x16x32_f16(a, b, c, 0, 0, 0);
}
}  // namespace

__global__ __launch_bounds__(512, 2) void lstm_g4(
    const float* __restrict__ x,      // [B][60]
    const float* __restrict__ w_ih,   // [200]
    const float* __restrict__ w_hh,   // [200][50]
    const float* __restrict__ b_ih,   // [200]
    const float* __restrict__ b_hh,   // [200]
    const float* __restrict__ w_lin,  // [3000]
    const float* __restrict__ b_lin,  // [1]
    float* __restrict__ out)          // [B]
{
  __shared__ __align__(16) _Float16 Hs[4][2][16 * 64];  // 16 KB [grp][buf]
  __shared__ float WL[TS * 64];  // 15.36 KB [t][u], 0-padded
  __shared__ float XL[TS * 64];  // 15.36 KB [t][b 0..63]
  __shared__ float OB[8][16];    // 512 B

  const int tid = threadIdx.x;
  const int lane = tid & 63;
  const int wv = tid >> 6;       // 0..7
  const int grp = wv >> 1;       // group 0..3 (one per wave-pair)
  const int half_ = wv & 1;      // M-half: 0 -> tiles 0..6, 1 -> tiles 7..12
  const int g = lane >> 4;       // B k-owner / D row-block (du)
  const int cl = lane & 15;      // batch-in-group; A/B/D column
  const int s8 = cl & 7;
  const long bbase = (long)blockIdx.x * 64;

  const int ntile = 7 - half_;   // 7 or 6
  const int Tbase = 7 * half_;

  // ---- stage XL[t][b] (coalesced over the block's 64x60 slice) ----
  for (int i = tid; i < TS * 64; i += 512) {
    const int b = i / TS, t = i - b * TS;
    XL[t * 64 + b] = x[bbase * TS + i];
  }
  // ---- stage WL[t][u] ----
  for (int i = tid; i < TS * 64; i += 512) {
    const int t = i >> 6, u = i & 63;
    WL[i] = (u < 50) ? w_lin[t * 50 + u] : 0.0f;
  }
  // ---- zero all H buffers (h0=0; pad k-slots stay 0) ----
  for (int i = tid; i < 4096; i += 512) ((unsigned*)Hs)[i] = 0u;

  // ---- gather this wave's A-fragments (fp32 -> fp16), once ----
  // tile T: A-row m=cl -> (du=cl>>2, gate=cl&3), unit uA = 4T+du,
  // orig gate-row = gate*50+uA. k-slot 32kc+8g+e: k<50 -> w_hh col k,
  // 62 -> bias, 63 -> w_ih.
  half8 A[7][2];
  {
    const int gate = cl & 3, du = cl >> 2;
#pragma unroll
    for (int tau = 0; tau < 7; ++tau) {
      const int T = Tbase + tau;
      const int uA = 4 * T + du;
      const int orig = gate * 50 + uA;
      const bool valid = (tau < ntile) && (uA < 50);
#pragma unroll
      for (int kc = 0; kc < 2; ++kc) {
        half8 fr;
#pragma unroll
        for (int e = 0; e < 8; ++e) {
          const int k = kc * 32 + 8 * g + e;
          float v = 0.0f;
          if (valid) {
            if (k < 50) v = w_hh[orig * 50 + k];
            else if (k == 62) v = b_ih[orig] + b_hh[orig];
            else if (k == 63) v = w_ih[orig];
          }
          fr[e] = (_Float16)v;
        }
        A[tau][kc] = fr;
      }
    }
  }
  __syncthreads();

  // ---- specials in buf0 of own group: k=62 -> 1.0, k=63 -> x_0 ----
  if (half_ == 1 && g == 3) {
    const half2v sp = {(_Float16)1.0f, (_Float16)XL[grp * 16 + cl]};
    *(half2v*)&Hs[grp][0][cl * 64 + ((7 ^ s8) << 3) + 6] = sp;
  }
  __syncthreads();

  // B-frag read offsets (halves): kc0 -> chunk g, kc1 -> chunk 4+g
  const int rh0 = cl * 64 + ((g ^ s8) << 3);
  const int rh1 = cl * 64 + (((4 | g) ^ s8) << 3);

  float c[7] = {0.f, 0.f, 0.f, 0.f, 0.f, 0.f, 0.f};
  float oacc = 0.0f;

  constexpr float L1 = 1.4426950408889634f;  // log2(e)
  constexpr float L2 = 2.8853900817779268f;  // 2*log2(e)

#pragma unroll 1
  for (int t = 0; t < TS; ++t) {
    const int p = t & 1;
    const _Float16* HR = &Hs[grp][p][0];
    _Float16* HW = &Hs[grp][p ^ 1][0];
    const half8 B0 = *(const half8*)&HR[rh0];
    const half8 B1 = *(const half8*)&HR[rh1];

    f32x4 acc[7];
#pragma unroll
    for (int tau = 0; tau < 7; ++tau) {
      if (tau < ntile) {
        f32x4 a = {0.f, 0.f, 0.f, 0.f};
        a = mfma16(A[tau][0], B0, a);
        a = mfma16(A[tau][1], B1, a);
        acc[tau] = a;
      }
    }
#pragma unroll
    for (int tau = 0; tau < 7; ++tau) {
      if (tau < ntile) {
        const int u = 4 * (Tbase + tau) + g;
        const float wlv = WL[t * 64 + u];
        const float E1 = fexp2(-L1 * acc[tau][0]);
        const float E2 = fexp2(-L1 * acc[tau][1]);
        const float E3 = fexp2(-L1 * acc[tau][3]);
        const float E4 = fexp2(L2 * acc[tau][2]);
        const float P1 = 1.0f + E1, P2 = 1.0f + E2;
        const float P3 = 1.0f + E3, P4 = 1.0f + E4;
        const float p12 = P1 * P2, p34 = P3 * P4;
        const float r = frcp(p12 * p34);
        const float r12 = r * p34, r34 = r * p12;
        const float si = r12 * P2, sf = r12 * P1, so = r34 * P4;
        const float tg = fmaf(-2.0f, r34 * P3, 1.0f);
        const float cn = fmaf(sf, c[tau], si * tg);
        c[tau] = cn;
        const float Ec = fexp2(L2 * cn);
        const float tc = fmaf(-2.0f, frcp(1.0f + Ec), 1.0f);
        const float hn = so * tc;
        oacc = fmaf(hn, wlv, oacc);
        HW[cl * 64 + (((u >> 3) ^ s8) << 3) + (u & 7)] = (_Float16)hn;
      }
    }
    if (half_ == 1 && g == 3) {  // specials for next step
      const int tn = (t + 1 < TS) ? (t + 1) : (TS - 1);
      const half2v sp = {(_Float16)1.0f, (_Float16)XL[tn * 64 + grp * 16 + cl]};
      *(half2v*)&HW[cl * 64 + ((7 ^ s8) << 3) + 6] = sp;
    }
    __syncthreads();
  }

  // ---- reduce over g (shfl), then combine the two waves per group ----
  oacc += __shfl_xor(oacc, 32);
  oacc += __shfl_xor(oacc, 16);
  if (lane < 16) OB[wv][cl] = oacc;
  __syncthreads();
  if (tid < 64) {
    const int gq = tid >> 4, b = tid & 15;
    out[bbase + tid] = OB[2 * gq][b] + OB[2 * gq + 1][b] + b_lin[0];
  }
}

extern "C" void kernel_launch(void* const* d_in, const int* in_sizes, int n_in,
                              void* d_out, int out_size, void* d_ws, size_t ws_size,
                              hipStream_t stream) {
  const float* x     = (const float*)d_in[0];
  const float* w_ih  = (const float*)d_in[1];
  const float* w_hh  = (const float*)d_in[2];
  const float* b_ih  = (const float*)d_in[3];
  const float* b_hh  = (const float*)d_in[4];
  const float* w_lin = (const float*)d_in[5];
  const float* b_lin = (const float*)d_in[6];
  float* out = (float*)d_out;

  dim3 grid(16384 / 64);  // 256 blocks -> 1 per CU
  dim3 block(512);
  lstm_g4<<<grid, block, 0, stream>>>(x, w_ih, w_hh, b_ih, b_hh, w_lin,
                                      b_lin, out);
}